// Round 3
// baseline (115.318 us; speedup 1.0000x reference)
//
#include <hip/hip_runtime.h>

#define BN_EPS 1e-5f
#define ALPHA 0.5f
#define BETA 0.5f

// B=32, C=1024, W=32, H=32, K=2.
// Batches processed in 2 groups of 16 so that each group's fm (64 MB) stays
// resident in the 256 MB Infinity Cache between the conv pass and the out
// pass (64 fm + 128 out-writes = 192 MB < 256 MB).
//
// Workspace (floats):
//   part_w [16][64][1024] at ws + 0        (1,048,576 floats, 4 MB)
//   part_h [16][64][1024] at ws + 1<<20    (4 MB)
//   fac    [32][4] float2 at ws + 1<<21    (256 floats)

typedef float vfloat4 __attribute__((ext_vector_type(4)));

// Block = (local batch bl, 16-channel chunk ch). Thread t owns spatial
// float4 pos t. Wave reads 64 consecutive float4 = 1 KB fully coalesced;
// weights are wave-uniform (scalar loads). No atomics: per-chunk partial
// conv sums stored to ws.
__global__ __launch_bounds__(256) void k_conv(
    const float* __restrict__ fm, const float* __restrict__ wW,
    const float* __restrict__ wH, float* __restrict__ part_w,
    float* __restrict__ part_h, int b0) {
  const int blk = blockIdx.x;     // 1024 = 16 * 64
  const int bl = blk >> 6;        // local batch
  const int ch = blk & 63;        // channel chunk (16 channels)
  const int t = threadIdx.x;      // spatial float4 pos 0..255
  const vfloat4* f4 = reinterpret_cast<const vfloat4*>(fm) +
                      ((size_t)((b0 + bl) * 1024 + ch * 16) * 256 + t);
  vfloat4 aw = {0.f, 0.f, 0.f, 0.f};
  vfloat4 ah = {0.f, 0.f, 0.f, 0.f};
#pragma unroll
  for (int c = 0; c < 16; ++c) {
    const vfloat4 v = f4[(size_t)c * 256];
    const float sw = wW[ch * 16 + c];  // uniform -> s_load
    const float sh = wH[ch * 16 + c];
    aw += v * sw;
    ah += v * sh;
  }
  const int o = (bl * 64 + ch) * 256 + t;
  reinterpret_cast<vfloat4*>(part_w)[o] = aw;
  reinterpret_cast<vfloat4*>(part_h)[o] = ah;
}

// One block per batch in the group: reduce the 64 chunk-partials per spatial
// position, BN+ReLU, strip-pool, softmax, emit (boost, mask) factors.
__global__ __launch_bounds__(256) void k_mid(
    const float* __restrict__ part_w, const float* __restrict__ part_h,
    const float* __restrict__ bw, const float* __restrict__ gw,
    const float* __restrict__ betw, const float* __restrict__ mw,
    const float* __restrict__ vw, const float* __restrict__ bh,
    const float* __restrict__ gh, const float* __restrict__ beth,
    const float* __restrict__ mh, const float* __restrict__ vh,
    float2* __restrict__ fac, int b0) {
  __shared__ vfloat4 red[4];
  const int bl = blockIdx.x;  // 0..15
  const int t = threadIdx.x;  // spatial float4 pos
  const vfloat4* pw4 =
      reinterpret_cast<const vfloat4*>(part_w) + bl * 16384 + t;
  const vfloat4* ph4 =
      reinterpret_cast<const vfloat4*>(part_h) + bl * 16384 + t;
  vfloat4 cw = {0.f, 0.f, 0.f, 0.f};
  vfloat4 chv = {0.f, 0.f, 0.f, 0.f};
#pragma unroll 8
  for (int k = 0; k < 64; ++k) {
    cw += pw4[k * 256];
    chv += ph4[k * 256];
  }
  const float scale_w = gw[0] * rsqrtf(vw[0] + BN_EPS);
  const float shift_w = (bw[0] - mw[0]) * scale_w + betw[0];
  const float scale_h = gh[0] * rsqrtf(vh[0] + BN_EPS);
  const float shift_h = (bh[0] - mh[0]) * scale_h + beth[0];

  const float aws = fmaxf(fmaf(cw.x, scale_w, shift_w), 0.f) +
                    fmaxf(fmaf(cw.y, scale_w, shift_w), 0.f) +
                    fmaxf(fmaf(cw.z, scale_w, shift_w), 0.f) +
                    fmaxf(fmaf(cw.w, scale_w, shift_w), 0.f);
  const float ahs = fmaxf(fmaf(chv.x, scale_h, shift_h), 0.f) +
                    fmaxf(fmaf(chv.y, scale_h, shift_h), 0.f) +
                    fmaxf(fmaf(chv.z, scale_h, shift_h), 0.f) +
                    fmaxf(fmaf(chv.w, scale_h, shift_h), 0.f);
  // thread t covers elems e=4t..4t+3: w = t>>3 (kw = t>>7), h = 4(t&7)+j
  // all in strip kh = (t&7)>>2.
  const int kw = t >> 7;
  const int kh = (t & 7) >> 2;
  vfloat4 s;
  s.x = kw ? 0.f : aws;
  s.y = kw ? aws : 0.f;
  s.z = kh ? 0.f : ahs;
  s.w = kh ? ahs : 0.f;
#pragma unroll
  for (int off = 32; off >= 1; off >>= 1) {
    s.x += __shfl_xor(s.x, off);
    s.y += __shfl_xor(s.y, off);
    s.z += __shfl_xor(s.z, off);
    s.w += __shfl_xor(s.w, off);
  }
  if ((t & 63) == 0) red[t >> 6] = s;
  __syncthreads();
  if (t == 0) {
    const vfloat4 a = red[0] + red[1] + red[2] + red[3];
    const float pw0 = a.x * (1.f / 512.f), pw1 = a.y * (1.f / 512.f);
    const float ph0 = a.z * (1.f / 512.f), ph1 = a.w * (1.f / 512.f);
    const float mwv = fmaxf(pw0, pw1);
    const float ew0 = __expf(pw0 - mwv), ew1 = __expf(pw1 - mwv);
    const float sw0 = ew0 / (ew0 + ew1), sw1 = ew1 / (ew0 + ew1);
    const float mhv = fmaxf(ph0, ph1);
    const float eh0 = __expf(ph0 - mhv), eh1 = __expf(ph1 - mhv);
    const float sh0 = eh0 / (eh0 + eh1), sh1 = eh1 / (eh0 + eh1);
    float f[4];
    f[0] = sw0 * sh0;
    f[1] = sw0 * sh1;
    f[2] = sw1 * sh0;
    f[3] = sw1 * sh1;
    const float thr = fmaxf(fmaxf(f[0], f[1]), fmaxf(f[2], f[3])) * 0.95f;
#pragma unroll
    for (int q = 0; q < 4; ++q) {
      fac[(b0 + bl) * 4 + q] =
          make_float2(1.f + ALPHA * f[q], (f[q] < thr) ? 1.f : BETA);
    }
  }
}

// Elementwise output pass over one 16-batch group (64 MB read, 128 MB write).
__global__ __launch_bounds__(256) void k_out(
    const float* __restrict__ fm, const float2* __restrict__ fac,
    float* __restrict__ out0, float* __restrict__ out1, int b0) {
  const size_t base = (size_t)b0 << 18;  // group start, float4 units
  const size_t i0 = (size_t)blockIdx.x * 256 + threadIdx.x;
  const vfloat4* fm4 = reinterpret_cast<const vfloat4*>(fm);
  vfloat4* o0 = reinterpret_cast<vfloat4*>(out0);
  vfloat4* o1 = reinterpret_cast<vfloat4*>(out1);
#pragma unroll
  for (int k = 0; k < 4; ++k) {
    const size_t i = base + i0 + (size_t)k * 1048576;
    const size_t e = i * 4;
    const int b = (int)(e >> 20);
    const int kw = ((int)(e >> 5) & 31) >> 4;
    const int kh = ((int)e & 31) >> 4;
    const float2 f = fac[(b << 2) | (kw << 1) | kh];
    const vfloat4 v = fm4[i];
    __builtin_nontemporal_store(v * f.x, &o0[i]);
    __builtin_nontemporal_store(v * f.y, &o1[i]);
  }
}

extern "C" void kernel_launch(void* const* d_in, const int* in_sizes, int n_in,
                              void* d_out, int out_size, void* d_ws,
                              size_t ws_size, hipStream_t stream) {
  const float* fm = (const float*)d_in[0];
  const float* w_w = (const float*)d_in[1];
  const float* b_w = (const float*)d_in[2];
  const float* g_w = (const float*)d_in[3];
  const float* be_w = (const float*)d_in[4];
  const float* m_w = (const float*)d_in[5];
  const float* v_w = (const float*)d_in[6];
  const float* w_h = (const float*)d_in[7];
  const float* b_h = (const float*)d_in[8];
  const float* g_h = (const float*)d_in[9];
  const float* be_h = (const float*)d_in[10];
  const float* m_h = (const float*)d_in[11];
  const float* v_h = (const float*)d_in[12];

  float* ws = (float*)d_ws;
  float* part_w = ws;                          // 4 MB
  float* part_h = ws + (1 << 20);              // 4 MB
  float2* fac = (float2*)(ws + (1 << 21));     // 32*4 float2

  float* out0 = (float*)d_out;
  float* out1 = out0 + (size_t)32 * 1024 * 1024;

  for (int g = 0; g < 2; ++g) {
    const int b0 = g * 16;
    k_conv<<<1024, 256, 0, stream>>>(fm, w_w, w_h, part_w, part_h, b0);
    k_mid<<<16, 256, 0, stream>>>(part_w, part_h, b_w, g_w, be_w, m_w, v_w,
                                  b_h, g_h, be_h, m_h, v_h, fac, b0);
    k_out<<<4096, 256, 0, stream>>>(fm, fac, out0, out1, b0);
  }
}